// Round 5
// baseline (233.846 us; speedup 1.0000x reference)
//
#include <hip/hip_runtime.h>
#include <hip/hip_bf16.h>
#include <math.h>

#define IMG 1024
#define NPIXTOT (IMG * IMG)
#define TWO_PI_F 6.28318530717958647692f

typedef __attribute__((ext_vector_type(8))) short short8;
typedef __attribute__((ext_vector_type(4))) float f32x4;
typedef unsigned int uint;
typedef unsigned short ushort;

// A-fragment weight image (W^T) in d_ws, bf16. Per layer: tile t = nt*KS+ks,
// element (t*512 + (hi*16+lo)*8 + i)  <->  A[m = nt*16+lo][k = ks*32+hi*8+i].
// Layers 2..4: k-axis permuted by permM so producer D-frag == consumer B-frag.
#define A1_OFF 0        // L1: NT=4, KS=4 (K 108->128; k=108 row = b1, x108=1)
#define A2_OFF 8192     // L2: NT=8, KS=2
#define A3_OFF 16384    // L3: NT=4, KS=4
#define A4_OFF 24576    // L4: NT=1, KS=2 (m 4->16 zero-pad)
#define WTOT   25600

#define XROW 136        // feature row stride: 272 B = 17*16 (b128-aligned, ~2-way banks)

__device__ __forceinline__ ushort f2bf(float f) {   // RNE f32->bf16
    uint u = __float_as_uint(f);
    u += 0x7fffu + ((u >> 16) & 1u);
    return (ushort)(u >> 16);
}
__device__ __forceinline__ uint pack2(float a, float b) {  // v_cvt_pk_bf16_f32
    float2 t; t.x = a; t.y = b;
    __hip_bfloat162 h = __float22bfloat162_rn(t);
    union { __hip_bfloat162 h; uint u; } cv; cv.h = h;
    return cv.u;
}
__device__ __forceinline__ float sig_fast(float x) {
    return __builtin_amdgcn_rcpf(1.0f + __expf(-x));
}

// GELU via 257-entry LDS table on [-8,8], h=1/16, linear interp (err ~3e-4).
// Above +8 the linear-extension term max(x-8,0) restores y = x exactly.
__device__ __forceinline__ float gelu_lut(float x, const float* __restrict__ g) {
    float t = __builtin_amdgcn_fmed3f(fmaf(x, 16.0f, 128.0f), 0.0f, 255.99609375f);
    int i = (int)t;                  // trunc; t >= 0
    float f = t - (float)i;
    float v0 = g[i], v1 = g[i + 1];  // ds_read2_b32
    float y = fmaf(f, v1 - v0, v0);
    return y + fmaxf(x - 8.0f, 0.0f);
}

// producer-neuron index feeding consumer k-position k (layers 2..4)
__device__ __forceinline__ int permM(int k) {
    return (2 * (k >> 5) + ((k >> 2) & 1)) * 16 + 4 * ((k >> 3) & 3) + (k & 3);
}

__global__ void prep_weights(const float* __restrict__ W1, const float* __restrict__ b1,
                             const float* __restrict__ W2, const float* __restrict__ W3,
                             const float* __restrict__ W4, ushort* __restrict__ ws) {
    int e = blockIdx.x * 256 + threadIdx.x;
    if (e >= WTOT) return;
    float v;
    if (e < A2_OFF) {                       // L1: identity k (features), bias row at k=108
        int i = e & 7, lo = (e >> 3) & 15, hi = (e >> 7) & 3, kst = e >> 9;
        int nt = kst >> 2, ks = kst & 3;
        int m = nt * 16 + lo, k = ks * 32 + hi * 8 + i;
        v = (k < 108) ? W1[k * 64 + m] : (k == 108 ? b1[m] : 0.0f);
    } else if (e < A3_OFF) {                // L2: K=64 permuted
        int r = e - A2_OFF, i = r & 7, lo = (r >> 3) & 15, hi = (r >> 7) & 3, kst = r >> 9;
        int nt = kst >> 1, ks = kst & 1;
        int m = nt * 16 + lo, k = ks * 32 + hi * 8 + i;
        v = W2[permM(k) * 128 + m];
    } else if (e < A4_OFF) {                // L3: K=128 permuted
        int r = e - A3_OFF, i = r & 7, lo = (r >> 3) & 15, hi = (r >> 7) & 3, kst = r >> 9;
        int nt = kst >> 2, ks = kst & 3;
        int m = nt * 16 + lo, k = ks * 32 + hi * 8 + i;
        v = W3[permM(k) * 64 + m];
    } else {                                // L4: K=64 permuted, m padded 4->16
        int r = e - A4_OFF, i = r & 7, lo = (r >> 3) & 15, hi = (r >> 7) & 3, ks = (r >> 9) & 1;
        int k = ks * 32 + hi * 8 + i;
        v = (lo < 4) ? W4[permM(k) * 4 + lo] : 0.0f;
    }
    ws[e] = f2bf(v);
}

// One layer fully in registers; GELU via LDS LUT. All indices compile-time.
template<int KS, int KSN, bool HASB>
__device__ __forceinline__ void mlayer_reg(const short8 (&bin)[2][KS], short8 (&bout)[2][KSN],
                                           const ushort* __restrict__ wA,
                                           const float* __restrict__ bias,
                                           const float* __restrict__ glut, int lo, int hi) {
    #pragma unroll
    for (int kn = 0; kn < KSN; ++kn) {
        f32x4 acc[2][2];   // [b = nt parity][pixel tile]
        #pragma unroll
        for (int b = 0; b < 2; ++b) {
            const int nt = 2 * kn + b;
            if (HASB) {
                const float4 bv = *(const float4*)&bias[nt * 16 + hi * 4];
                acc[b][0] = f32x4{bv.x, bv.y, bv.z, bv.w};
            } else {
                acc[b][0] = f32x4{0.f, 0.f, 0.f, 0.f};
            }
            acc[b][1] = acc[b][0];
            #pragma unroll
            for (int ks = 0; ks < KS; ++ks) {
                const short8 a = *(const short8*)&wA[(nt * KS + ks) * 512 + (hi * 16 + lo) * 8];
                acc[b][0] = __builtin_amdgcn_mfma_f32_16x16x32_bf16(a, bin[0][ks], acc[b][0], 0, 0, 0);
                acc[b][1] = __builtin_amdgcn_mfma_f32_16x16x32_bf16(a, bin[1][ks], acc[b][1], 0, 0, 0);
            }
        }
        #pragma unroll
        for (int pt = 0; pt < 2; ++pt) {
            union { short8 s; uint u[4]; } o;
            o.u[0] = pack2(gelu_lut(acc[0][pt][0], glut), gelu_lut(acc[0][pt][1], glut));
            o.u[1] = pack2(gelu_lut(acc[0][pt][2], glut), gelu_lut(acc[0][pt][3], glut));
            o.u[2] = pack2(gelu_lut(acc[1][pt][0], glut), gelu_lut(acc[1][pt][1], glut));
            o.u[3] = pack2(gelu_lut(acc[1][pt][2], glut), gelu_lut(acc[1][pt][3], glut));
            bout[pt][kn] = o.s;
        }
    }
}

__global__ __launch_bounds__(256, 4) void vfx_mfma(
    const float* __restrict__ latent, const int* __restrict__ raw_pos,
    const float* __restrict__ control, const ushort* __restrict__ wA,
    const float* __restrict__ b2, const float* __restrict__ b3,
    const float* __restrict__ b4, float* __restrict__ out)
{
    __shared__ ushort lds[4 * 32 * XROW];   // 34,816 B
    __shared__ float  glut[257];            // 1,028 B  : gelu on [-8,8], h=1/16
    __shared__ uint   slut[1024];           // 4,096 B  : (sin(2pi k/1024), sin(4pi k/1024)) bf16x2
    const int tid = threadIdx.x;
    const int wave = tid >> 6, lane = tid & 63;
    const int lo = lane & 15, hi = lane >> 4;
    ushort* xw = lds + wave * 32 * XROW;
    const int pixbase = blockIdx.x * 128 + wave * 32;

    // ---- build LUTs (block-shared) ----
    for (int i = tid; i < 1024; i += 256) {
        const float a = (float)i * (1.0f / 1024.0f);
        slut[i] = pack2(sinf(TWO_PI_F * a), sinf(2.0f * TWO_PI_F * a));
    }
    for (int i = tid; i < 257; i += 256) {
        const float x = (float)i * 0.0625f - 8.0f;
        glut[i] = 0.5f * x * (1.0f + erff(x * 0.70710678118654752440f));
    }
    __syncthreads();   // the only barrier: tables ready

    // ---- build X^T in LDS: row = pixel (32), k = 0..107 features, 108 = 1.0 ----
    {
        const int p = lane & 31;
        const int g = pixbase + p;
        const int2 rp = ((const int2*)raw_pos)[g];
        const float2 cf = ((const float2*)control)[g];
        ushort* xrow = xw + p * XROW;
        const int nb0 = (lane < 32) ? 0 : 5;
        const int nbn = (lane < 32) ? 5 : 4;
        for (int t = 0; t < nbn; ++t) {
            const int nb = nb0 + t;
            const int ex = min(max(rp.x + nb / 3 - 1, 0), IMG - 1);
            const int ey = min(max(rp.y + (nb % 3) - 1, 0), IMG - 1);
            const float4 lat = ((const float4*)latent)[ey * IMG + ex];
            const float xf = ex * (1.0f / IMG), yf = ey * (1.0f / IMG);
            const uint sx = slut[ex], sy = slut[ey];   // exact sin at integer grid
            const int e = nb * 12;
            *(uint*)&xrow[e + 0]  = pack2(lat.x, lat.y);
            *(uint*)&xrow[e + 2]  = pack2(lat.z, lat.w);
            *(uint*)&xrow[e + 4]  = pack2(xf, yf);
            *(uint*)&xrow[e + 6]  = (sx & 0xffffu) | (sy << 16);          // s1x|s1y
            *(uint*)&xrow[e + 8]  = (sx >> 16) | (sy & 0xffff0000u);      // s2x|s2y
            *(uint*)&xrow[e + 10] = pack2(cf.x, cf.y);
        }
        if (lane >= 32) {   // k=108 -> 1.0 (bias feature), 109..127 -> 0
            *(uint*)&xrow[108] = 0x3f80u;
            #pragma unroll
            for (int e2 = 110; e2 < 128; e2 += 2) *(uint*)&xrow[e2] = 0u;
        }
    }

    // ---- L1 B-frags from LDS, then the whole MLP stays in registers ----
    short8 bX[2][4];
    #pragma unroll
    for (int pt = 0; pt < 2; ++pt)
        #pragma unroll
        for (int ks = 0; ks < 4; ++ks)
            bX[pt][ks] = *(const short8*)&xw[(pt * 16 + lo) * XROW + ks * 32 + hi * 8];

    short8 h1[2][2], h2[2][4], h3[2][2];
    mlayer_reg<4, 2, false>(bX, h1, wA + A1_OFF, nullptr, glut, lo, hi);  // 128 -> 64
    mlayer_reg<2, 4, true >(h1, h2, wA + A2_OFF, b2, glut, lo, hi);       // 64  -> 128
    mlayer_reg<4, 2, true >(h2, h3, wA + A3_OFF, b3, glut, lo, hi);       // 128 -> 64

    // ---- L4: 64 -> 4 (m-padded 16), sigmoid, float4 store ----
    {
        float4 bv = {0.f, 0.f, 0.f, 0.f};
        if (hi == 0) bv = *(const float4*)b4;
        f32x4 acc0 = {bv.x, bv.y, bv.z, bv.w};
        f32x4 acc1 = acc0;
        #pragma unroll
        for (int ks = 0; ks < 2; ++ks) {
            const short8 a = *(const short8*)&wA[A4_OFF + (ks * 512) + (hi * 16 + lo) * 8];
            acc0 = __builtin_amdgcn_mfma_f32_16x16x32_bf16(a, h3[0][ks], acc0, 0, 0, 0);
            acc1 = __builtin_amdgcn_mfma_f32_16x16x32_bf16(a, h3[1][ks], acc1, 0, 0, 0);
        }
        if (hi == 0) {   // rows 0..3 = the 4 outputs, col = pixel lo
            float4 o;
            o.x = sig_fast(acc0[0]); o.y = sig_fast(acc0[1]);
            o.z = sig_fast(acc0[2]); o.w = sig_fast(acc0[3]);
            *(float4*)&out[(pixbase + lo) * 4] = o;
            o.x = sig_fast(acc1[0]); o.y = sig_fast(acc1[1]);
            o.z = sig_fast(acc1[2]); o.w = sig_fast(acc1[3]);
            *(float4*)&out[(pixbase + 16 + lo) * 4] = o;
        }
    }
}

extern "C" void kernel_launch(void* const* d_in, const int* in_sizes, int n_in,
                              void* d_out, int out_size, void* d_ws, size_t ws_size,
                              hipStream_t stream) {
    const float* latent  = (const float*)d_in[0];
    const int*   raw_pos = (const int*)  d_in[1];
    const float* control = (const float*)d_in[2];
    const float* W1 = (const float*)d_in[3];
    const float* b1 = (const float*)d_in[4];
    const float* W2 = (const float*)d_in[5];
    const float* b2 = (const float*)d_in[6];
    const float* W3 = (const float*)d_in[7];
    const float* b3 = (const float*)d_in[8];
    const float* W4 = (const float*)d_in[9];
    const float* b4 = (const float*)d_in[10];
    float* out = (float*)d_out;
    ushort* ws = (ushort*)d_ws;

    prep_weights<<<dim3((WTOT + 255) / 256), dim3(256), 0, stream>>>(W1, b1, W2, W3, W4, ws);

    dim3 grid(NPIXTOT / 128);   // 8192 blocks x 256 threads, 128 pixels/block
    vfx_mfma<<<grid, dim3(256), 0, stream>>>(
        latent, raw_pos, control, ws, b2, b3, b4, out);
}

// Round 6
// 123.819 us; speedup vs baseline: 1.8886x; 1.8886x over previous
//
#include <hip/hip_runtime.h>
#include <hip/hip_bf16.h>
#include <math.h>

#define IMG 1024
#define NPIXTOT (IMG * IMG)

typedef __attribute__((ext_vector_type(8))) short short8;
typedef __attribute__((ext_vector_type(4))) float f32x4;
typedef unsigned int uint;
typedef unsigned short ushort;

// A-fragment weight image (W^T) in d_ws, bf16. Per layer: tile t = nt*KS+ks,
// element (t*512 + (hi*16+lo)*8 + i)  <->  A[m = nt*16+lo][k = ks*32+hi*8+i].
// Layers 2..4: k-axis permuted by permM so producer D-frag == consumer B-frag.
#define A1_OFF 0        // L1: NT=4, KS=4 (K 108->128; k=108 row = b1, x108=1)
#define A2_OFF 8192     // L2: NT=8, KS=2
#define A3_OFF 16384    // L3: NT=4, KS=4
#define A4_OFF 24576    // L4: NT=1, KS=2 (m 4->16 zero-pad)
#define WTOT   25600
// GELU direct-lookup table appended to the weight image:
#define GLUT_N   3072   // [-6,6), h=1/256; entry i = bf16(gelu((i-1536)/256))
#define GLUT_OFF WTOT
#define WSTOT    (WTOT + GLUT_N)

#define XROW 136        // feature row stride: 272 B = 17*16 (b128-aligned)

__device__ __forceinline__ ushort f2bf(float f) {   // RNE f32->bf16
    uint u = __float_as_uint(f);
    u += 0x7fffu + ((u >> 16) & 1u);
    return (ushort)(u >> 16);
}
__device__ __forceinline__ uint pack2(float a, float b) {  // v_cvt_pk_bf16_f32
    float2 t; t.x = a; t.y = b;
    __hip_bfloat162 h = __float22bfloat162_rn(t);
    union { __hip_bfloat162 h; uint u; } cv; cv.h = h;
    return cv.u;
}
__device__ __forceinline__ float sig_fast(float x) {
    return __builtin_amdgcn_rcpf(1.0f + __expf(-x));
}

// GELU via direct bf16 lookup: round(x*256)+1536, clamped to [0, 3071].
// Returns the final bf16 bit pattern (no pack needed). err <= ~2.2e-3 + bf16 ulp.
__device__ __forceinline__ ushort gelu16(float x, const ushort* __restrict__ g) {
    float t = __builtin_amdgcn_fmed3f(fmaf(x, 256.0f, 1536.5f), 0.0f, 3071.0f);
    return g[(int)t];
}

// producer-neuron index feeding consumer k-position k (layers 2..4)
__device__ __forceinline__ int permM(int k) {
    return (2 * (k >> 5) + ((k >> 2) & 1)) * 16 + 4 * ((k >> 3) & 3) + (k & 3);
}

__global__ void prep_weights(const float* __restrict__ W1, const float* __restrict__ b1,
                             const float* __restrict__ W2, const float* __restrict__ W3,
                             const float* __restrict__ W4, ushort* __restrict__ ws) {
    int e = blockIdx.x * 256 + threadIdx.x;
    if (e >= WSTOT) return;
    float v;
    if (e < A2_OFF) {                       // L1: identity k (features), bias row at k=108
        int i = e & 7, lo = (e >> 3) & 15, hi = (e >> 7) & 3, kst = e >> 9;
        int nt = kst >> 2, ks = kst & 3;
        int m = nt * 16 + lo, k = ks * 32 + hi * 8 + i;
        v = (k < 108) ? W1[k * 64 + m] : (k == 108 ? b1[m] : 0.0f);
    } else if (e < A3_OFF) {                // L2: K=64 permuted
        int r = e - A2_OFF, i = r & 7, lo = (r >> 3) & 15, hi = (r >> 7) & 3, kst = r >> 9;
        int nt = kst >> 1, ks = kst & 1;
        int m = nt * 16 + lo, k = ks * 32 + hi * 8 + i;
        v = W2[permM(k) * 128 + m];
    } else if (e < A4_OFF) {                // L3: K=128 permuted
        int r = e - A3_OFF, i = r & 7, lo = (r >> 3) & 15, hi = (r >> 7) & 3, kst = r >> 9;
        int nt = kst >> 2, ks = kst & 3;
        int m = nt * 16 + lo, k = ks * 32 + hi * 8 + i;
        v = W3[permM(k) * 64 + m];
    } else if (e < GLUT_OFF) {              // L4: K=64 permuted, m padded 4->16
        int r = e - A4_OFF, i = r & 7, lo = (r >> 3) & 15, hi = (r >> 7) & 3, ks = (r >> 9) & 1;
        int k = ks * 32 + hi * 8 + i;
        v = (lo < 4) ? W4[permM(k) * 4 + lo] : 0.0f;
    } else {                                // GELU table
        const float x = (float)(e - GLUT_OFF - 1536) * (1.0f / 256.0f);
        v = 0.5f * x * (1.0f + erff(x * 0.70710678118654752440f));
    }
    ws[e] = f2bf(v);
}

// One layer fully in registers; GELU via direct bf16 LDS lookup.
template<int KS, int KSN, bool HASB>
__device__ __forceinline__ void mlayer_reg(const short8 (&bin)[2][KS], short8 (&bout)[2][KSN],
                                           const ushort* __restrict__ wA,
                                           const float* __restrict__ bias,
                                           const ushort* __restrict__ gl, int lo, int hi) {
    #pragma unroll
    for (int kn = 0; kn < KSN; ++kn) {
        f32x4 acc[2][2];   // [b = nt parity][pixel tile]
        #pragma unroll
        for (int b = 0; b < 2; ++b) {
            const int nt = 2 * kn + b;
            if (HASB) {
                const float4 bv = *(const float4*)&bias[nt * 16 + hi * 4];
                acc[b][0] = f32x4{bv.x, bv.y, bv.z, bv.w};
            } else {
                acc[b][0] = f32x4{0.f, 0.f, 0.f, 0.f};
            }
            acc[b][1] = acc[b][0];
            #pragma unroll
            for (int ks = 0; ks < KS; ++ks) {
                const short8 a = *(const short8*)&wA[(nt * KS + ks) * 512 + (hi * 16 + lo) * 8];
                acc[b][0] = __builtin_amdgcn_mfma_f32_16x16x32_bf16(a, bin[0][ks], acc[b][0], 0, 0, 0);
                acc[b][1] = __builtin_amdgcn_mfma_f32_16x16x32_bf16(a, bin[1][ks], acc[b][1], 0, 0, 0);
            }
        }
        #pragma unroll
        for (int pt = 0; pt < 2; ++pt) {
            union { short8 s; uint u[4]; } o;
            o.u[0] = (uint)gelu16(acc[0][pt][0], gl) | ((uint)gelu16(acc[0][pt][1], gl) << 16);
            o.u[1] = (uint)gelu16(acc[0][pt][2], gl) | ((uint)gelu16(acc[0][pt][3], gl) << 16);
            o.u[2] = (uint)gelu16(acc[1][pt][0], gl) | ((uint)gelu16(acc[1][pt][1], gl) << 16);
            o.u[3] = (uint)gelu16(acc[1][pt][2], gl) | ((uint)gelu16(acc[1][pt][3], gl) << 16);
            bout[pt][kn] = o.s;
        }
    }
}

__global__ __launch_bounds__(256, 4) void vfx_mfma(
    const float* __restrict__ latent, const int* __restrict__ raw_pos,
    const float* __restrict__ control, const ushort* __restrict__ wA,
    const float* __restrict__ b2, const float* __restrict__ b3,
    const float* __restrict__ b4, float* __restrict__ out)
{
    __shared__ ushort lds[4 * 32 * XROW];   // 34,816 B
    __shared__ ushort glut[GLUT_N];         //  6,144 B  -> total 40,960 B = 4 blocks/CU
    const int tid = threadIdx.x;
    const int wave = tid >> 6, lane = tid & 63;
    const int lo = lane & 15, hi = lane >> 4;
    ushort* xw = lds + wave * 32 * XROW;
    const int pixbase = blockIdx.x * 128 + wave * 32;

    // ---- stage GELU table to LDS (384 uint4; overlaps with feature build) ----
    {
        const uint4* src = (const uint4*)(wA + GLUT_OFF);
        uint4* dst = (uint4*)glut;
        #pragma unroll
        for (int it = 0; it < 2; ++it) {
            const int i = tid + it * 256;
            if (i < GLUT_N / 8) dst[i] = src[i];
        }
    }

    // ---- build X^T in LDS: row = pixel (32), k = 0..107 features, 108 = 1.0 ----
    {
        const int p = lane & 31;
        const int g = pixbase + p;
        const int2 rp = ((const int2*)raw_pos)[g];
        const float2 cf = ((const float2*)control)[g];
        ushort* xrow = xw + p * XROW;
        const int nb0 = (lane < 32) ? 0 : 5;
        const int nbn = (lane < 32) ? 5 : 4;
        for (int t = 0; t < nbn; ++t) {
            const int nb = nb0 + t;
            const int ex = min(max(rp.x + nb / 3 - 1, 0), IMG - 1);
            const int ey = min(max(rp.y + (nb % 3) - 1, 0), IMG - 1);
            const float4 lat = ((const float4*)latent)[ey * IMG + ex];
            const float xf = ex * (1.0f / IMG), yf = ey * (1.0f / IMG);
            // v_sin_f32 takes revolutions; xf,yf in [0,1) already
            const float s1x = __builtin_amdgcn_sinf(xf);
            const float s1y = __builtin_amdgcn_sinf(yf);
            const float s2x = __builtin_amdgcn_sinf(__builtin_amdgcn_fractf(2.0f * xf));
            const float s2y = __builtin_amdgcn_sinf(__builtin_amdgcn_fractf(2.0f * yf));
            const int e = nb * 12;
            *(uint*)&xrow[e + 0]  = pack2(lat.x, lat.y);
            *(uint*)&xrow[e + 2]  = pack2(lat.z, lat.w);
            *(uint*)&xrow[e + 4]  = pack2(xf, yf);
            *(uint*)&xrow[e + 6]  = pack2(s1x, s1y);
            *(uint*)&xrow[e + 8]  = pack2(s2x, s2y);
            *(uint*)&xrow[e + 10] = pack2(cf.x, cf.y);
        }
        if (lane >= 32) {   // k=108 -> 1.0 (bias feature), 109..127 -> 0
            *(uint*)&xrow[108] = 0x3f80u;
            #pragma unroll
            for (int e2 = 110; e2 < 128; e2 += 2) *(uint*)&xrow[e2] = 0u;
        }
    }
    __syncthreads();   // table (block-shared) + own X ready

    // ---- L1 B-frags from LDS, then the whole MLP stays in registers ----
    short8 bX[2][4];
    #pragma unroll
    for (int pt = 0; pt < 2; ++pt)
        #pragma unroll
        for (int ks = 0; ks < 4; ++ks)
            bX[pt][ks] = *(const short8*)&xw[(pt * 16 + lo) * XROW + ks * 32 + hi * 8];

    short8 h1[2][2], h2[2][4], h3[2][2];
    mlayer_reg<4, 2, false>(bX, h1, wA + A1_OFF, nullptr, glut, lo, hi);  // 128 -> 64
    mlayer_reg<2, 4, true >(h1, h2, wA + A2_OFF, b2, glut, lo, hi);       // 64  -> 128
    mlayer_reg<4, 2, true >(h2, h3, wA + A3_OFF, b3, glut, lo, hi);       // 128 -> 64

    // ---- L4: 64 -> 4 (m-padded 16), sigmoid, float4 store ----
    {
        float4 bv = {0.f, 0.f, 0.f, 0.f};
        if (hi == 0) bv = *(const float4*)b4;
        f32x4 acc0 = {bv.x, bv.y, bv.z, bv.w};
        f32x4 acc1 = acc0;
        #pragma unroll
        for (int ks = 0; ks < 2; ++ks) {
            const short8 a = *(const short8*)&wA[A4_OFF + (ks * 512) + (hi * 16 + lo) * 8];
            acc0 = __builtin_amdgcn_mfma_f32_16x16x32_bf16(a, h3[0][ks], acc0, 0, 0, 0);
            acc1 = __builtin_amdgcn_mfma_f32_16x16x32_bf16(a, h3[1][ks], acc1, 0, 0, 0);
        }
        if (hi == 0) {   // rows 0..3 = the 4 outputs, col = pixel lo
            float4 o;
            o.x = sig_fast(acc0[0]); o.y = sig_fast(acc0[1]);
            o.z = sig_fast(acc0[2]); o.w = sig_fast(acc0[3]);
            *(float4*)&out[(pixbase + lo) * 4] = o;
            o.x = sig_fast(acc1[0]); o.y = sig_fast(acc1[1]);
            o.z = sig_fast(acc1[2]); o.w = sig_fast(acc1[3]);
            *(float4*)&out[(pixbase + 16 + lo) * 4] = o;
        }
    }
}

extern "C" void kernel_launch(void* const* d_in, const int* in_sizes, int n_in,
                              void* d_out, int out_size, void* d_ws, size_t ws_size,
                              hipStream_t stream) {
    const float* latent  = (const float*)d_in[0];
    const int*   raw_pos = (const int*)  d_in[1];
    const float* control = (const float*)d_in[2];
    const float* W1 = (const float*)d_in[3];
    const float* b1 = (const float*)d_in[4];
    const float* W2 = (const float*)d_in[5];
    const float* b2 = (const float*)d_in[6];
    const float* W3 = (const float*)d_in[7];
    const float* b3 = (const float*)d_in[8];
    const float* W4 = (const float*)d_in[9];
    const float* b4 = (const float*)d_in[10];
    float* out = (float*)d_out;
    ushort* ws = (ushort*)d_ws;

    prep_weights<<<dim3((WSTOT + 255) / 256), dim3(256), 0, stream>>>(W1, b1, W2, W3, W4, ws);

    dim3 grid(NPIXTOT / 128);   // 8192 blocks x 256 threads, 128 pixels/block
    vfx_mfma<<<grid, dim3(256), 0, stream>>>(
        latent, raw_pos, control, ws, b2, b3, b4, out);
}